// Round 1
// baseline (748.884 us; speedup 1.0000x reference)
//
#include <hip/hip_runtime.h>
#include <math.h>

#define B_   16
#define N_   2048
#define KNN  20
#define OD   64
#define M_TOT (B_ * N_ * KNN)

// ---------------------------------------------------------------------------
// K1: brute-force KNN (top-20 by -||xi-xj||^2, tie -> lower j, matches
// lax.top_k), split j-range in 2 halves per point for occupancy, then merge.
// Also accumulates the 27 global moments of f = [xj-xi (3), xi (3)].
// ---------------------------------------------------------------------------
__global__ __launch_bounds__(256) void k1_knn(const float* __restrict__ x,
                                              float* __restrict__ stats,
                                              int* __restrict__ idxbuf) {
    __shared__ float4 pts[N_];          // (x,y,z,||x||^2)  32 KB
    __shared__ float  mlist[256][21];   // padded stride 21: conflict-light
    __shared__ int    ilist[256][21];

    const int b     = blockIdx.x >> 4;   // 16 chunks of 128 points per batch
    const int chunk = blockIdx.x & 15;
    const int t     = threadIdx.x;

    const float* xb = x + b * 3 * N_;
    for (int n = t; n < N_; n += 256) {
        float x0 = xb[n], x1 = xb[N_ + n], x2 = xb[2 * N_ + n];
        float xx = x0 * x0;
        xx = fmaf(x1, x1, xx);
        xx = fmaf(x2, x2, xx);
        pts[n] = make_float4(x0, x1, x2, xx);
    }
    __syncthreads();

    const int il   = chunk * 128 + (t & 127);  // my point index
    const int half = t >> 7;                   // which 1024-j half I scan
    const float4 pi = pts[il];

    float d[KNN];
    int   id[KNN];
#pragma unroll
    for (int s = 0; s < KNN; ++s) { d[s] = -INFINITY; id[s] = 0; }

    const int j0 = half << 10;
    for (int j = j0; j < j0 + 1024; ++j) {
        float4 p = pts[j];                       // broadcast read
        float dot = pi.x * p.x;
        dot = fmaf(pi.y, p.y, dot);
        dot = fmaf(pi.z, p.z, dot);
        // pd = 2*dot - xx_i - xx_j ; for i==j this is exactly 0 in fp32
        float pd = fmaf(2.f, dot, -pi.w) - p.w;
        if (pd > d[KNN - 1]) {                   // strict >: stable ties
            float vd = pd; int vi = j;
#pragma unroll
            for (int s = 0; s < KNN; ++s) {      // branchless sorted insert
                bool  c   = vd > d[s];
                float nd  = c ? vd : d[s];
                float nv  = c ? d[s] : vd;
                int   ni  = c ? vi : id[s];
                int   nvi = c ? id[s] : vi;
                d[s] = nd; vd = nv; id[s] = ni; vi = nvi;
            }
        }
    }

#pragma unroll
    for (int s = 0; s < KNN; ++s) { mlist[t][s] = d[s]; ilist[t][s] = id[s]; }
    __syncthreads();

    if (t < 128) {  // waves 0-1: merge half0 (mine) with half1 (t+128)
        int pa = 0, pb = 0;
        int ri[KNN];
#pragma unroll
        for (int r = 0; r < KNN; ++r) {
            float av = mlist[t][pa], bv = mlist[t + 128][pb];
            bool ta = (av >= bv);               // tie -> half0 = lower j
            ri[r] = ta ? ilist[t][pa] : ilist[t + 128][pb];
            pa += ta ? 1 : 0;
            pb += ta ? 0 : 1;
        }

        int* op = idxbuf + (b * N_ + il) * KNN;
#pragma unroll
        for (int r = 0; r < KNN; ++r) op[r] = ri[r];

        // moments of f = [e0,e1,e2, c0,c1,c2], e = xj - xi, c = xi
        float se0 = 0.f, se1 = 0.f, se2 = 0.f;
        float see[6] = {0.f, 0.f, 0.f, 0.f, 0.f, 0.f};
#pragma unroll
        for (int r = 0; r < KNN; ++r) {
            float4 pj = pts[ri[r]];
            float e0 = pj.x - pi.x, e1 = pj.y - pi.y, e2 = pj.z - pi.z;
            se0 += e0; se1 += e1; se2 += e2;
            see[0] = fmaf(e0, e0, see[0]);
            see[1] = fmaf(e0, e1, see[1]);
            see[2] = fmaf(e0, e2, see[2]);
            see[3] = fmaf(e1, e1, see[3]);
            see[4] = fmaf(e1, e2, see[4]);
            see[5] = fmaf(e2, e2, see[5]);
        }
        float c0 = pi.x, c1 = pi.y, c2 = pi.z;
        float v[27];
        v[0] = se0; v[1] = se1; v[2] = se2;
        v[3] = 20.f * c0; v[4] = 20.f * c1; v[5] = 20.f * c2;
        v[6]  = see[0];      // (0,0)
        v[7]  = see[1];      // (0,1)
        v[8]  = see[2];      // (0,2)
        v[9]  = se0 * c0;    // (0,3)
        v[10] = se0 * c1;    // (0,4)
        v[11] = se0 * c2;    // (0,5)
        v[12] = see[3];      // (1,1)
        v[13] = see[4];      // (1,2)
        v[14] = se1 * c0;    // (1,3)
        v[15] = se1 * c1;    // (1,4)
        v[16] = se1 * c2;    // (1,5)
        v[17] = see[5];      // (2,2)
        v[18] = se2 * c0;    // (2,3)
        v[19] = se2 * c1;    // (2,4)
        v[20] = se2 * c2;    // (2,5)
        v[21] = 20.f * c0 * c0;  // (3,3)
        v[22] = 20.f * c0 * c1;  // (3,4)
        v[23] = 20.f * c0 * c2;  // (3,5)
        v[24] = 20.f * c1 * c1;  // (4,4)
        v[25] = 20.f * c1 * c2;  // (4,5)
        v[26] = 20.f * c2 * c2;  // (5,5)

#pragma unroll
        for (int m = 0; m < 27; ++m) {
            float s = v[m];
#pragma unroll
            for (int off = 32; off > 0; off >>= 1) s += __shfl_xor(s, off);
            if ((t & 63) == 0) atomicAdd(stats + m, s);
        }
    }
}

// ---------------------------------------------------------------------------
// K2: finalize BN stats -> fused weights W' = scale*W, shift = beta - mean*scale
// ---------------------------------------------------------------------------
__global__ void k2_fin(const float* __restrict__ stats, const float* __restrict__ W,
                       const float* __restrict__ bnw, const float* __restrict__ bnb,
                       float* __restrict__ wp) {
    const int o = threadIdx.x;  // 64 threads
    float m[6];
#pragma unroll
    for (int c = 0; c < 6; ++c) m[c] = stats[c];
    float S[6][6];
    int p = 6;
#pragma unroll
    for (int a = 0; a < 6; ++a)
#pragma unroll
        for (int bb = a; bb < 6; ++bb) { S[a][bb] = stats[p]; S[bb][a] = stats[p]; ++p; }
    float w[6];
#pragma unroll
    for (int c = 0; c < 6; ++c) w[c] = W[o * 6 + c];

    const float invM = 1.f / (float)M_TOT;
    float mean = 0.f;
#pragma unroll
    for (int c = 0; c < 6; ++c) mean += w[c] * m[c];
    mean *= invM;
    float ey2 = 0.f;
#pragma unroll
    for (int a = 0; a < 6; ++a)
#pragma unroll
        for (int bb = 0; bb < 6; ++bb) ey2 += w[a] * w[bb] * S[a][bb];
    ey2 *= invM;
    float var   = ey2 - mean * mean;
    float scale = bnw[o] * rsqrtf(var + 1e-5f);
    float shift = bnb[o] - mean * scale;
#pragma unroll
    for (int c = 0; c < 6; ++c) wp[o * 8 + c] = w[c] * scale;
    wp[o * 8 + 6] = shift;
    wp[o * 8 + 7] = 0.f;
}

// ---------------------------------------------------------------------------
// K3: per (b,n): gather 20 neighbor deltas, 64-channel fused conv+BN+relu+max
// ---------------------------------------------------------------------------
__global__ __launch_bounds__(256) void k3_out(const float* __restrict__ x,
                                              const float* __restrict__ wp,
                                              const int* __restrict__ idxbuf,
                                              float* __restrict__ out) {
    __shared__ float4 pts[N_];
    __shared__ float  lwp[OD * 8];

    const int b     = blockIdx.x >> 3;  // 8 chunks of 256 points per batch
    const int chunk = blockIdx.x & 7;
    const int t     = threadIdx.x;

    const float* xb = x + b * 3 * N_;
    for (int n = t; n < N_; n += 256)
        pts[n] = make_float4(xb[n], xb[N_ + n], xb[2 * N_ + n], 0.f);
    for (int q = t; q < OD * 8; q += 256) lwp[q] = wp[q];
    __syncthreads();

    const int n = chunk * 256 + t;
    const float4 pi = pts[n];
    const int* ip = idxbuf + (b * N_ + n) * KNN;

    float e0[KNN], e1[KNN], e2[KNN];
#pragma unroll
    for (int r = 0; r < KNN; ++r) {
        int j = ip[r];
        float4 pj = pts[j];
        e0[r] = pj.x - pi.x;
        e1[r] = pj.y - pi.y;
        e2[r] = pj.z - pi.z;
    }

    float* ob = out + (size_t)b * OD * N_ + n;
#pragma unroll 8
    for (int o = 0; o < OD; ++o) {
        float w0 = lwp[o * 8 + 0], w1 = lwp[o * 8 + 1], w2 = lwp[o * 8 + 2];
        float w3 = lwp[o * 8 + 3], w4 = lwp[o * 8 + 4], w5 = lwp[o * 8 + 5];
        float base = lwp[o * 8 + 6];
        base = fmaf(w3, pi.x, base);
        base = fmaf(w4, pi.y, base);
        base = fmaf(w5, pi.z, base);
        float acc = 0.f;  // relu: max(0, .) folded into init
#pragma unroll
        for (int r = 0; r < KNN; ++r) {
            float y = base;
            y = fmaf(w0, e0[r], y);
            y = fmaf(w1, e1[r], y);
            y = fmaf(w2, e2[r], y);
            acc = fmaxf(acc, y);
        }
        ob[(size_t)o * N_] = acc;
    }
}

// ---------------------------------------------------------------------------
extern "C" void kernel_launch(void* const* d_in, const int* in_sizes, int n_in,
                              void* d_out, int out_size, void* d_ws, size_t ws_size,
                              hipStream_t stream) {
    const float* x   = (const float*)d_in[0];
    const float* W   = (const float*)d_in[1];
    const float* bnw = (const float*)d_in[2];
    const float* bnb = (const float*)d_in[3];
    float* out = (float*)d_out;

    float* stats  = (float*)d_ws;                       // 27 floats
    float* wp     = (float*)((char*)d_ws + 1024);       // 64*8 floats
    int*   idxbuf = (int*)((char*)d_ws + 4096);         // B*N*K ints (~2.6 MB)

    hipMemsetAsync(d_ws, 0, 128, stream);
    k1_knn<<<dim3(256), dim3(256), 0, stream>>>(x, stats, idxbuf);
    k2_fin<<<dim3(1), dim3(64), 0, stream>>>(stats, W, bnw, bnb, wp);
    k3_out<<<dim3(128), dim3(256), 0, stream>>>(x, wp, idxbuf, out);
}

// Round 2
// 446.763 us; speedup vs baseline: 1.6762x; 1.6762x over previous
//
#include <hip/hip_runtime.h>
#include <math.h>

#define B_   16
#define N_   2048
#define KNN  20
#define OD   64
#define M_TOT (B_ * N_ * KNN)

typedef unsigned long long u64;

// ---------------------------------------------------------------------------
// K1: brute-force KNN. 64 points/block, 4 threads per point (each scans 512
// candidates), u64 (value,~index) keys -> exact lax.top_k tie semantics.
// 512 blocks x 256 threads, 2 blocks/CU. Also accumulates the 27 global
// moments of f = [xj-xi (3), xi (3)].
// ---------------------------------------------------------------------------
__global__ __launch_bounds__(256, 2) void k1_knn(const float* __restrict__ x,
                                                 float* __restrict__ stats,
                                                 int* __restrict__ idxbuf) {
    __shared__ float4 pts[N_];          // (x,y,z,||x||^2)  32 KB
    __shared__ u64    mbuf[256][21];    // sorted top-20 per thread, pad 21

    const int b     = blockIdx.x >> 5;   // 32 chunks of 64 points per batch
    const int chunk = blockIdx.x & 31;
    const int t     = threadIdx.x;

    const float* xb = x + b * 3 * N_;
    for (int n = t; n < N_; n += 256) {
        float x0 = xb[n], x1 = xb[N_ + n], x2 = xb[2 * N_ + n];
        float xx = x0 * x0;
        xx = fmaf(x1, x1, xx);
        xx = fmaf(x2, x2, xx);
        pts[n] = make_float4(x0, x1, x2, xx);
    }
    __syncthreads();

    const int p  = t & 63;               // my point within chunk
    const int s  = t >> 6;               // which quarter of j-range I scan
    const int il = chunk * 64 + p;
    const float4 pi = pts[il];

    u64 d[KNN];
#pragma unroll
    for (int q = 0; q < KNN; ++q) d[q] = 0ull;  // below any real key

    auto process = [&](const float4& pj, int j) {
        float dot = pi.x * pj.x;
        dot = fmaf(pi.y, pj.y, dot);
        dot = fmaf(pi.z, pj.z, dot);
        // pd = 2*dot - xx_i - xx_j ; exactly 0 for i==j (matches reference)
        float pd = fmaf(2.f, dot, -pi.w) - pj.w;
        unsigned u = __float_as_uint(pd);
        u = ((int)u < 0) ? ~u : (u | 0x80000000u);   // monotone float->uint
        u64 key = ((u64)u << 32) | (unsigned)(~j);   // tie -> lower j larger
        if (key > d[KNN - 1]) {
            u64 v = key;
#pragma unroll
            for (int q = 0; q < KNN; ++q) {          // branchless sorted insert
                bool c  = v > d[q];
                u64 nd  = c ? v : d[q];
                v       = c ? d[q] : v;
                d[q]    = nd;
            }
        }
    };

    const int j0 = s << 9;                           // s*512
    for (int jj = 0; jj < 512; jj += 4) {
        int j = j0 + jj;
        float4 q0 = pts[j + 0];
        float4 q1 = pts[j + 1];
        float4 q2 = pts[j + 2];
        float4 q3 = pts[j + 3];
        process(q0, j + 0);
        process(q1, j + 1);
        process(q2, j + 2);
        process(q3, j + 3);
    }

#pragma unroll
    for (int q = 0; q < KNN; ++q) mbuf[t][q] = d[q];
    __syncthreads();

    if (t < 64) {  // wave 0: 4-way merge per point, then stats
        u64 h[4];
        int c[4];
#pragma unroll
        for (int q = 0; q < 4; ++q) { h[q] = mbuf[t + 64 * q][0]; c[q] = 1; }

        int ri[KNN];
#pragma unroll
        for (int r = 0; r < KNN; ++r) {
            int w = 0; u64 best = h[0];
            if (h[1] > best) { best = h[1]; w = 1; }
            if (h[2] > best) { best = h[2]; w = 2; }
            if (h[3] > best) { best = h[3]; w = 3; }
            ri[r] = ~(unsigned)best;                  // recover index
#pragma unroll
            for (int q = 0; q < 4; ++q)
                if (w == q) {
                    h[q] = (c[q] < KNN) ? mbuf[t + 64 * q][c[q]] : 0ull;
                    c[q]++;
                }
        }

        int* op = idxbuf + (b * N_ + il) * KNN;
#pragma unroll
        for (int r = 0; r < KNN; ++r) op[r] = ri[r];

        // moments of f = [e0,e1,e2, c0,c1,c2], e = xj - xi, c = xi
        float se0 = 0.f, se1 = 0.f, se2 = 0.f;
        float see[6] = {0.f, 0.f, 0.f, 0.f, 0.f, 0.f};
#pragma unroll
        for (int r = 0; r < KNN; ++r) {
            float4 pj = pts[ri[r]];
            float e0 = pj.x - pi.x, e1 = pj.y - pi.y, e2 = pj.z - pi.z;
            se0 += e0; se1 += e1; se2 += e2;
            see[0] = fmaf(e0, e0, see[0]);
            see[1] = fmaf(e0, e1, see[1]);
            see[2] = fmaf(e0, e2, see[2]);
            see[3] = fmaf(e1, e1, see[3]);
            see[4] = fmaf(e1, e2, see[4]);
            see[5] = fmaf(e2, e2, see[5]);
        }
        float c0 = pi.x, c1 = pi.y, c2 = pi.z;
        float v[27];
        v[0] = se0; v[1] = se1; v[2] = se2;
        v[3] = 20.f * c0; v[4] = 20.f * c1; v[5] = 20.f * c2;
        v[6]  = see[0];
        v[7]  = see[1];
        v[8]  = see[2];
        v[9]  = se0 * c0;
        v[10] = se0 * c1;
        v[11] = se0 * c2;
        v[12] = see[3];
        v[13] = see[4];
        v[14] = se1 * c0;
        v[15] = se1 * c1;
        v[16] = se1 * c2;
        v[17] = see[5];
        v[18] = se2 * c0;
        v[19] = se2 * c1;
        v[20] = se2 * c2;
        v[21] = 20.f * c0 * c0;
        v[22] = 20.f * c0 * c1;
        v[23] = 20.f * c0 * c2;
        v[24] = 20.f * c1 * c1;
        v[25] = 20.f * c1 * c2;
        v[26] = 20.f * c2 * c2;

#pragma unroll
        for (int m = 0; m < 27; ++m) {
            float sm = v[m];
#pragma unroll
            for (int off = 32; off > 0; off >>= 1) sm += __shfl_xor(sm, off);
            if (t == 0) atomicAdd(stats + m, sm);
        }
    }
}

// ---------------------------------------------------------------------------
// K2: finalize BN stats -> fused weights W' = scale*W, shift = beta - mean*scale
// ---------------------------------------------------------------------------
__global__ void k2_fin(const float* __restrict__ stats, const float* __restrict__ W,
                       const float* __restrict__ bnw, const float* __restrict__ bnb,
                       float* __restrict__ wp) {
    const int o = threadIdx.x;  // 64 threads
    float m[6];
#pragma unroll
    for (int c = 0; c < 6; ++c) m[c] = stats[c];
    float S[6][6];
    int p = 6;
#pragma unroll
    for (int a = 0; a < 6; ++a)
#pragma unroll
        for (int bb = a; bb < 6; ++bb) { S[a][bb] = stats[p]; S[bb][a] = stats[p]; ++p; }
    float w[6];
#pragma unroll
    for (int c = 0; c < 6; ++c) w[c] = W[o * 6 + c];

    const float invM = 1.f / (float)M_TOT;
    float mean = 0.f;
#pragma unroll
    for (int c = 0; c < 6; ++c) mean += w[c] * m[c];
    mean *= invM;
    float ey2 = 0.f;
#pragma unroll
    for (int a = 0; a < 6; ++a)
#pragma unroll
        for (int bb = 0; bb < 6; ++bb) ey2 += w[a] * w[bb] * S[a][bb];
    ey2 *= invM;
    float var   = ey2 - mean * mean;
    float scale = bnw[o] * rsqrtf(var + 1e-5f);
    float shift = bnb[o] - mean * scale;
#pragma unroll
    for (int c = 0; c < 6; ++c) wp[o * 8 + c] = w[c] * scale;
    wp[o * 8 + 6] = shift;
    wp[o * 8 + 7] = 0.f;
}

// ---------------------------------------------------------------------------
// K3: per (b,n): gather 20 neighbor deltas, 64-channel fused conv+BN+relu+max
// 256 blocks x 128 threads (1 point/thread) -> all CUs busy.
// ---------------------------------------------------------------------------
__global__ __launch_bounds__(128) void k3_out(const float* __restrict__ x,
                                              const float* __restrict__ wp,
                                              const int* __restrict__ idxbuf,
                                              float* __restrict__ out) {
    __shared__ float4 pts[N_];
    __shared__ float  lwp[OD * 8];

    const int b     = blockIdx.x >> 4;  // 16 chunks of 128 points per batch
    const int chunk = blockIdx.x & 15;
    const int t     = threadIdx.x;

    const float* xb = x + b * 3 * N_;
    for (int n = t; n < N_; n += 128)
        pts[n] = make_float4(xb[n], xb[N_ + n], xb[2 * N_ + n], 0.f);
    for (int q = t; q < OD * 8; q += 128) lwp[q] = wp[q];
    __syncthreads();

    const int n = chunk * 128 + t;
    const float4 pi = pts[n];
    const int* ip = idxbuf + (b * N_ + n) * KNN;

    float e0[KNN], e1[KNN], e2[KNN];
#pragma unroll
    for (int r = 0; r < KNN; ++r) {
        int j = ip[r];
        float4 pj = pts[j];
        e0[r] = pj.x - pi.x;
        e1[r] = pj.y - pi.y;
        e2[r] = pj.z - pi.z;
    }

    float* ob = out + (size_t)b * OD * N_ + n;
#pragma unroll 8
    for (int o = 0; o < OD; ++o) {
        float w0 = lwp[o * 8 + 0], w1 = lwp[o * 8 + 1], w2 = lwp[o * 8 + 2];
        float w3 = lwp[o * 8 + 3], w4 = lwp[o * 8 + 4], w5 = lwp[o * 8 + 5];
        float base = lwp[o * 8 + 6];
        base = fmaf(w3, pi.x, base);
        base = fmaf(w4, pi.y, base);
        base = fmaf(w5, pi.z, base);
        float acc = 0.f;  // relu folded into init
#pragma unroll
        for (int r = 0; r < KNN; ++r) {
            float y = base;
            y = fmaf(w0, e0[r], y);
            y = fmaf(w1, e1[r], y);
            y = fmaf(w2, e2[r], y);
            acc = fmaxf(acc, y);
        }
        ob[(size_t)o * N_] = acc;
    }
}

// ---------------------------------------------------------------------------
extern "C" void kernel_launch(void* const* d_in, const int* in_sizes, int n_in,
                              void* d_out, int out_size, void* d_ws, size_t ws_size,
                              hipStream_t stream) {
    const float* x   = (const float*)d_in[0];
    const float* W   = (const float*)d_in[1];
    const float* bnw = (const float*)d_in[2];
    const float* bnb = (const float*)d_in[3];
    float* out = (float*)d_out;

    float* stats  = (float*)d_ws;                       // 27 floats
    float* wp     = (float*)((char*)d_ws + 1024);       // 64*8 floats
    int*   idxbuf = (int*)((char*)d_ws + 4096);         // B*N*K ints (~2.6 MB)

    hipMemsetAsync(d_ws, 0, 128, stream);
    k1_knn<<<dim3(512), dim3(256), 0, stream>>>(x, stats, idxbuf);
    k2_fin<<<dim3(1), dim3(64), 0, stream>>>(stats, W, bnw, bnb, wp);
    k3_out<<<dim3(256), dim3(128), 0, stream>>>(x, wp, idxbuf, out);
}

// Round 3
// 264.913 us; speedup vs baseline: 2.8269x; 1.6865x over previous
//
#include <hip/hip_runtime.h>
#include <math.h>

#define B_   16
#define N_   2048
#define KNN  20
#define OD   64
#define M_TOT (B_ * N_ * KNN)
#define PPB  64          // points per k1 block
#define NB   64          // histogram buckets (quarter-octave of |pd|)
#define CAP  89          // collect capacity per point (typ ~30)
#define BKT_BASE 468     // bucket = clamp((nk>>21)-468, 0, 63); d2=2^e -> 40+4e

typedef unsigned long long u64;
typedef unsigned int u32;

// ---------------------------------------------------------------------------
// K1: histogram-select KNN. 64 points/block, 4 threads/point (512 cand each).
// Pass A: bucket-count |pd|. Scan: per-point threshold covering >=20. Pass B:
// collect exact (monotone pd, ~j) keys above threshold. Pass C: exact top-20
// chain over ~30 entries (lax.top_k semantics: value desc, tie -> lower j).
// Also accumulates the 27 global moments of f = [xj-xi (3), xi (3)].
// ---------------------------------------------------------------------------
__global__ __launch_bounds__(256, 2) void k1_knn(const float* __restrict__ x,
                                                 float* __restrict__ stats,
                                                 int* __restrict__ idxbuf) {
    __shared__ float4 pts[N_];            // 32 KB  (x,y,z,||x||^2)
    __shared__ u64    coll[PPB][CAP];     // 45.5 KB; first 16 KB overlaid as hist
    __shared__ u32    pcnt[PPB];
    __shared__ u32    edgev[PPB];

    u32* hist = (u32*)&coll[0][0];        // [NB][PPB] transposed: bank = p&31

    const int b     = blockIdx.x >> 5;    // 32 chunks of 64 points per batch
    const int chunk = blockIdx.x & 31;
    const int t     = threadIdx.x;

    const float* xb = x + b * 3 * N_;
    for (int n = t; n < N_; n += 256) {
        float x0 = xb[n], x1 = xb[N_ + n], x2 = xb[2 * N_ + n];
        float xx = x0 * x0;
        xx = fmaf(x1, x1, xx);
        xx = fmaf(x2, x2, xx);
        pts[n] = make_float4(x0, x1, x2, xx);
    }
    {   // zero hist + counters
        uint4* h4 = (uint4*)hist;
        for (int i = t; i < NB * PPB / 4; i += 256) h4[i] = make_uint4(0, 0, 0, 0);
        if (t < PPB) pcnt[t] = 0;
    }
    __syncthreads();

    const int p  = t & 63;
    const int s  = t >> 6;
    const int il = chunk * 64 + p;
    const float4 pi = pts[il];
    const int j0 = s << 9;

    // ---- pass A: histogram of |pd| buckets --------------------------------
    {
        auto binit = [&](const float4& pj) {
            float dot = pi.x * pj.x;
            dot = fmaf(pi.y, pj.y, dot);
            dot = fmaf(pi.z, pj.z, dot);
            float pd = fmaf(2.f, dot, -pi.w) - pj.w;   // exactly 0 for i==j
            u32 nk = __float_as_uint(pd) & 0x7FFFFFFFu;
            int bkt = (int)(nk >> 21) - BKT_BASE;
            bkt = min(max(bkt, 0), 63);
            atomicAdd(&hist[bkt * PPB + p], 1u);
        };
        for (int jj = 0; jj < 512; jj += 4) {
            int j = j0 + jj;
            float4 q0 = pts[j + 0];
            float4 q1 = pts[j + 1];
            float4 q2 = pts[j + 2];
            float4 q3 = pts[j + 3];
            binit(q0); binit(q1); binit(q2); binit(q3);
        }
    }
    __syncthreads();

    // ---- scan: per-point threshold bucket ---------------------------------
    if (t < PPB) {
        int cum = 0, tau = 63;
        for (int k = 0; k < NB; ++k) {
            cum += (int)hist[k * PPB + t];
            if (cum >= KNN) { tau = k; break; }
        }
        edgev[t] = (u32)(BKT_BASE + 1 + tau) << 21;  // nk < edge <=> bucket <= tau
    }
    __syncthreads();

    // ---- pass B: collect exact keys above threshold -----------------------
    {
        const u32 edge = edgev[p];
        auto collect = [&](const float4& pj, int j) {
            float dot = pi.x * pj.x;
            dot = fmaf(pi.y, pj.y, dot);
            dot = fmaf(pi.z, pj.z, dot);
            float pd = fmaf(2.f, dot, -pi.w) - pj.w;
            u32 u = __float_as_uint(pd);
            u32 nk = u & 0x7FFFFFFFu;
            if (nk < edge) {
                u32 mono = ((int)u < 0) ? ~u : (u | 0x80000000u);
                u64 key = ((u64)mono << 32) | (u32)(~j);
                u32 pos = atomicAdd(&pcnt[p], 1u);
                if (pos < CAP) coll[p][pos] = key;
            }
        };
        for (int jj = 0; jj < 512; jj += 4) {
            int j = j0 + jj;
            float4 q0 = pts[j + 0];
            float4 q1 = pts[j + 1];
            float4 q2 = pts[j + 2];
            float4 q3 = pts[j + 3];
            collect(q0, j + 0); collect(q1, j + 1);
            collect(q2, j + 2); collect(q3, j + 3);
        }
    }
    __syncthreads();

    // ---- pass C: exact top-20 over collected, idx write, stats ------------
    if (t < PPB) {
        const int cnt = min((int)pcnt[t], CAP);
        u64 d[KNN];
#pragma unroll
        for (int q = 0; q < KNN; ++q) d[q] = 0ull;
        for (int e = 0; e < cnt; ++e) {
            u64 v = coll[t][e];
#pragma unroll
            for (int q = 0; q < KNN; ++q) {          // sorted CE chain
                u64 hi = (v > d[q]) ? v : d[q];
                u64 lo = (v > d[q]) ? d[q] : v;
                d[q] = hi; v = lo;
            }
        }
        int ri[KNN];
#pragma unroll
        for (int r = 0; r < KNN; ++r) ri[r] = ~(u32)d[r];

        int* op = idxbuf + (b * N_ + il) * KNN;
#pragma unroll
        for (int r = 0; r < KNN; ++r) op[r] = ri[r];

        // moments of f = [e0,e1,e2, c0,c1,c2], e = xj - xi, c = xi
        float se0 = 0.f, se1 = 0.f, se2 = 0.f;
        float see[6] = {0.f, 0.f, 0.f, 0.f, 0.f, 0.f};
#pragma unroll
        for (int r = 0; r < KNN; ++r) {
            float4 pj = pts[ri[r]];
            float e0 = pj.x - pi.x, e1 = pj.y - pi.y, e2 = pj.z - pi.z;
            se0 += e0; se1 += e1; se2 += e2;
            see[0] = fmaf(e0, e0, see[0]);
            see[1] = fmaf(e0, e1, see[1]);
            see[2] = fmaf(e0, e2, see[2]);
            see[3] = fmaf(e1, e1, see[3]);
            see[4] = fmaf(e1, e2, see[4]);
            see[5] = fmaf(e2, e2, see[5]);
        }
        float c0 = pi.x, c1 = pi.y, c2 = pi.z;
        float v[27];
        v[0] = se0; v[1] = se1; v[2] = se2;
        v[3] = 20.f * c0; v[4] = 20.f * c1; v[5] = 20.f * c2;
        v[6]  = see[0];
        v[7]  = see[1];
        v[8]  = see[2];
        v[9]  = se0 * c0;
        v[10] = se0 * c1;
        v[11] = se0 * c2;
        v[12] = see[3];
        v[13] = see[4];
        v[14] = se1 * c0;
        v[15] = se1 * c1;
        v[16] = se1 * c2;
        v[17] = see[5];
        v[18] = se2 * c0;
        v[19] = se2 * c1;
        v[20] = se2 * c2;
        v[21] = 20.f * c0 * c0;
        v[22] = 20.f * c0 * c1;
        v[23] = 20.f * c0 * c2;
        v[24] = 20.f * c1 * c1;
        v[25] = 20.f * c1 * c2;
        v[26] = 20.f * c2 * c2;

#pragma unroll
        for (int m = 0; m < 27; ++m) {
            float sm = v[m];
#pragma unroll
            for (int off = 32; off > 0; off >>= 1) sm += __shfl_xor(sm, off);
            if (t == 0) atomicAdd(stats + m, sm);
        }
    }
}

// ---------------------------------------------------------------------------
// K2: finalize BN stats -> fused weights W' = scale*W, shift = beta - mean*scale
// ---------------------------------------------------------------------------
__global__ void k2_fin(const float* __restrict__ stats, const float* __restrict__ W,
                       const float* __restrict__ bnw, const float* __restrict__ bnb,
                       float* __restrict__ wp) {
    const int o = threadIdx.x;  // 64 threads
    float m[6];
#pragma unroll
    for (int c = 0; c < 6; ++c) m[c] = stats[c];
    float S[6][6];
    int p = 6;
#pragma unroll
    for (int a = 0; a < 6; ++a)
#pragma unroll
        for (int bb = a; bb < 6; ++bb) { S[a][bb] = stats[p]; S[bb][a] = stats[p]; ++p; }
    float w[6];
#pragma unroll
    for (int c = 0; c < 6; ++c) w[c] = W[o * 6 + c];

    const float invM = 1.f / (float)M_TOT;
    float mean = 0.f;
#pragma unroll
    for (int c = 0; c < 6; ++c) mean += w[c] * m[c];
    mean *= invM;
    float ey2 = 0.f;
#pragma unroll
    for (int a = 0; a < 6; ++a)
#pragma unroll
        for (int bb = 0; bb < 6; ++bb) ey2 += w[a] * w[bb] * S[a][bb];
    ey2 *= invM;
    float var   = ey2 - mean * mean;
    float scale = bnw[o] * rsqrtf(var + 1e-5f);
    float shift = bnb[o] - mean * scale;
#pragma unroll
    for (int c = 0; c < 6; ++c) wp[o * 8 + c] = w[c] * scale;
    wp[o * 8 + 6] = shift;
    wp[o * 8 + 7] = 0.f;
}

// ---------------------------------------------------------------------------
// K3: per (b,n): gather 20 neighbor deltas, fused conv+BN+relu+max.
// 2 threads/point (32 channels each) -> 1024 waves.
// ---------------------------------------------------------------------------
__global__ __launch_bounds__(256) void k3_out(const float* __restrict__ x,
                                              const float* __restrict__ wp,
                                              const int* __restrict__ idxbuf,
                                              float* __restrict__ out) {
    __shared__ float4 pts[N_];
    __shared__ float  lwp[OD * 8];

    const int b     = blockIdx.x >> 4;  // 16 chunks of 128 points per batch
    const int chunk = blockIdx.x & 15;
    const int t     = threadIdx.x;

    const float* xb = x + b * 3 * N_;
    for (int n = t; n < N_; n += 256)
        pts[n] = make_float4(xb[n], xb[N_ + n], xb[2 * N_ + n], 0.f);
    for (int q = t; q < OD * 8; q += 256) lwp[q] = wp[q];
    __syncthreads();

    const int n = chunk * 128 + (t & 127);
    const int h = t >> 7;               // channel half: [h*32, h*32+32)
    const float4 pi = pts[n];
    const int* ip = idxbuf + (b * N_ + n) * KNN;

    float e0[KNN], e1[KNN], e2[KNN];
#pragma unroll
    for (int r = 0; r < KNN; ++r) {
        int j = ip[r];
        float4 pj = pts[j];
        e0[r] = pj.x - pi.x;
        e1[r] = pj.y - pi.y;
        e2[r] = pj.z - pi.z;
    }

    float* ob = out + (size_t)b * OD * N_ + n;
    const int o0 = h * 32;
#pragma unroll 8
    for (int o = o0; o < o0 + 32; ++o) {
        float w0 = lwp[o * 8 + 0], w1 = lwp[o * 8 + 1], w2 = lwp[o * 8 + 2];
        float w3 = lwp[o * 8 + 3], w4 = lwp[o * 8 + 4], w5 = lwp[o * 8 + 5];
        float base = lwp[o * 8 + 6];
        base = fmaf(w3, pi.x, base);
        base = fmaf(w4, pi.y, base);
        base = fmaf(w5, pi.z, base);
        float acc = 0.f;  // relu folded into init
#pragma unroll
        for (int r = 0; r < KNN; ++r) {
            float y = base;
            y = fmaf(w0, e0[r], y);
            y = fmaf(w1, e1[r], y);
            y = fmaf(w2, e2[r], y);
            acc = fmaxf(acc, y);
        }
        ob[(size_t)o * N_] = acc;
    }
}

// ---------------------------------------------------------------------------
extern "C" void kernel_launch(void* const* d_in, const int* in_sizes, int n_in,
                              void* d_out, int out_size, void* d_ws, size_t ws_size,
                              hipStream_t stream) {
    const float* x   = (const float*)d_in[0];
    const float* W   = (const float*)d_in[1];
    const float* bnw = (const float*)d_in[2];
    const float* bnb = (const float*)d_in[3];
    float* out = (float*)d_out;

    float* stats  = (float*)d_ws;                       // 27 floats
    float* wp     = (float*)((char*)d_ws + 1024);       // 64*8 floats
    int*   idxbuf = (int*)((char*)d_ws + 4096);         // B*N*K ints (~2.6 MB)

    hipMemsetAsync(d_ws, 0, 128, stream);
    k1_knn<<<dim3(512), dim3(256), 0, stream>>>(x, stats, idxbuf);
    k2_fin<<<dim3(1), dim3(64), 0, stream>>>(stats, W, bnw, bnb, wp);
    k3_out<<<dim3(256), dim3(256), 0, stream>>>(x, wp, idxbuf, out);
}

// Round 4
// 235.958 us; speedup vs baseline: 3.1738x; 1.1227x over previous
//
#include <hip/hip_runtime.h>
#include <math.h>

#define B_   16
#define N_   2048
#define KNN  20
#define OD   64
#define M_TOT (B_ * N_ * KNN)
#define PPB  64          // points per k1 block
#define NB   64          // histogram buckets (quarter-octave of |pd|)
#define CAP  96          // collect capacity per point (typ ~30)
#define BKT_BASE 468     // bucket = clamp((nk>>21)-468, 0, 63)

typedef unsigned long long u64;
typedef unsigned int u32;
typedef unsigned short u16;

// ---------------------------------------------------------------------------
// K1: histogram-select KNN. 64 points/block, 8 threads/point (256 cand each),
// 512 threads/block, 512 blocks -> 16 waves/CU. Pass A: bucket-count |pd|
// (LDS atomic, transposed layout, 8-wide read ILP). Scan: per-point threshold
// covering >=20. Pass B: collect u16 candidate indices above threshold.
// Pass C: recompute exact keys (bit-identical fma sequence), top-20 CE chain
// (lax.top_k semantics: value desc, tie -> lower j). Order of idx is
// irrelevant downstream (sum/max), only the exact SET matters.
// Also accumulates the 27 global moments of f = [xj-xi (3), xi (3)].
// ---------------------------------------------------------------------------
__global__ __launch_bounds__(512, 4) void k1_knn(const float* __restrict__ x,
                                                 float* __restrict__ stats,
                                                 int* __restrict__ idxbuf) {
    __shared__ float4 pts[N_];            // 32 KB  (x,y,z,||x||^2)
    __shared__ u32    hist[NB * PPB];     // 16 KB  [bkt][p] -> bank = p&31
    __shared__ u16    coll[PPB][CAP];     // 12 KB
    __shared__ u32    pcnt[PPB];
    __shared__ u32    edgev[PPB];

    const int b     = blockIdx.x >> 5;    // 32 chunks of 64 points per batch
    const int chunk = blockIdx.x & 31;
    const int t     = threadIdx.x;

    const float* xb = x + b * 3 * N_;
    for (int n = t; n < N_; n += 512) {
        float x0 = xb[n], x1 = xb[N_ + n], x2 = xb[2 * N_ + n];
        float xx = x0 * x0;
        xx = fmaf(x1, x1, xx);
        xx = fmaf(x2, x2, xx);
        pts[n] = make_float4(x0, x1, x2, xx);
    }
    for (int i = t; i < NB * PPB; i += 512) hist[i] = 0;
    if (t < PPB) pcnt[t] = 0;
    __syncthreads();

    const int p  = t & 63;                // my point within chunk (wave: 0..63)
    const int s  = t >> 6;                // my eighth of the j-range
    const int il = chunk * 64 + p;
    const float4 pi = pts[il];
    const int j0 = s << 8;                // s*256

    // ---- pass A: histogram of |pd| buckets (8-wide ILP) -------------------
    for (int jj = 0; jj < 256; jj += 8) {
        float4 q[8];
#pragma unroll
        for (int u = 0; u < 8; ++u) q[u] = pts[j0 + jj + u];
#pragma unroll
        for (int u = 0; u < 8; ++u) {
            float dot = pi.x * q[u].x;
            dot = fmaf(pi.y, q[u].y, dot);
            dot = fmaf(pi.z, q[u].z, dot);
            float pd = fmaf(2.f, dot, -pi.w) - q[u].w;   // exactly 0 for i==j
            u32 nk = __float_as_uint(pd) & 0x7FFFFFFFu;
            int bkt = (int)(nk >> 21) - BKT_BASE;
            bkt = min(max(bkt, 0), 63);
            atomicAdd(&hist[bkt * PPB + p], 1u);         // ds_add, no return
        }
    }
    __syncthreads();

    // ---- scan: per-point threshold bucket ---------------------------------
    if (t < PPB) {
        int cum = 0, tau = 63;
        for (int k = 0; k < NB; ++k) {
            cum += (int)hist[k * PPB + t];
            if (cum >= KNN) { tau = k; break; }
        }
        edgev[t] = (u32)(BKT_BASE + 1 + tau) << 21;  // nk < edge <=> bucket <= tau
    }
    __syncthreads();

    // ---- pass B: collect u16 indices above threshold ----------------------
    {
        const u32 edge = edgev[p];
        for (int jj = 0; jj < 256; jj += 8) {
            float4 q[8];
#pragma unroll
            for (int u = 0; u < 8; ++u) q[u] = pts[j0 + jj + u];
#pragma unroll
            for (int u = 0; u < 8; ++u) {
                float dot = pi.x * q[u].x;
                dot = fmaf(pi.y, q[u].y, dot);
                dot = fmaf(pi.z, q[u].z, dot);
                float pd = fmaf(2.f, dot, -pi.w) - q[u].w;
                u32 nk = __float_as_uint(pd) & 0x7FFFFFFFu;
                if (nk < edge) {
                    u32 pos = atomicAdd(&pcnt[p], 1u);
                    if (pos < CAP) coll[p][pos] = (u16)(j0 + jj + u);
                }
            }
        }
    }
    __syncthreads();

    // ---- pass C: exact top-20 over collected, idx write, stats ------------
    if (t < PPB) {
        const int cnt = min((int)pcnt[t], CAP);
        u64 d[KNN];
#pragma unroll
        for (int q = 0; q < KNN; ++q) d[q] = 0ull;
        for (int e = 0; e < cnt; ++e) {
            int j = coll[t][e];
            float4 pj = pts[j];
            float dot = pi.x * pj.x;
            dot = fmaf(pi.y, pj.y, dot);
            dot = fmaf(pi.z, pj.z, dot);
            float pd = fmaf(2.f, dot, -pi.w) - pj.w;     // bit-identical to pass B
            u32 u = __float_as_uint(pd);
            u32 mono = ((int)u < 0) ? ~u : (u | 0x80000000u);
            u64 v = ((u64)mono << 32) | (u32)(~j);
            if (v > d[KNN - 1]) {
#pragma unroll
                for (int q = 0; q < KNN; ++q) {          // sorted CE chain
                    u64 hi = (v > d[q]) ? v : d[q];
                    u64 lo = (v > d[q]) ? d[q] : v;
                    d[q] = hi; v = lo;
                }
            }
        }
        int ri[KNN];
#pragma unroll
        for (int r = 0; r < KNN; ++r) ri[r] = ~(u32)d[r];

        int* op = idxbuf + (b * N_ + il) * KNN;
#pragma unroll
        for (int r = 0; r < KNN; ++r) op[r] = ri[r];

        // moments of f = [e0,e1,e2, c0,c1,c2], e = xj - xi, c = xi
        float se0 = 0.f, se1 = 0.f, se2 = 0.f;
        float see[6] = {0.f, 0.f, 0.f, 0.f, 0.f, 0.f};
#pragma unroll
        for (int r = 0; r < KNN; ++r) {
            float4 pj = pts[ri[r]];
            float e0 = pj.x - pi.x, e1 = pj.y - pi.y, e2 = pj.z - pi.z;
            se0 += e0; se1 += e1; se2 += e2;
            see[0] = fmaf(e0, e0, see[0]);
            see[1] = fmaf(e0, e1, see[1]);
            see[2] = fmaf(e0, e2, see[2]);
            see[3] = fmaf(e1, e1, see[3]);
            see[4] = fmaf(e1, e2, see[4]);
            see[5] = fmaf(e2, e2, see[5]);
        }
        float c0 = pi.x, c1 = pi.y, c2 = pi.z;
        float v[27];
        v[0] = se0; v[1] = se1; v[2] = se2;
        v[3] = 20.f * c0; v[4] = 20.f * c1; v[5] = 20.f * c2;
        v[6]  = see[0];
        v[7]  = see[1];
        v[8]  = see[2];
        v[9]  = se0 * c0;
        v[10] = se0 * c1;
        v[11] = se0 * c2;
        v[12] = see[3];
        v[13] = see[4];
        v[14] = se1 * c0;
        v[15] = se1 * c1;
        v[16] = se1 * c2;
        v[17] = see[5];
        v[18] = se2 * c0;
        v[19] = se2 * c1;
        v[20] = se2 * c2;
        v[21] = 20.f * c0 * c0;
        v[22] = 20.f * c0 * c1;
        v[23] = 20.f * c0 * c2;
        v[24] = 20.f * c1 * c1;
        v[25] = 20.f * c1 * c2;
        v[26] = 20.f * c2 * c2;

#pragma unroll
        for (int m = 0; m < 27; ++m) {
            float sm = v[m];
#pragma unroll
            for (int off = 32; off > 0; off >>= 1) sm += __shfl_xor(sm, off);
            if (t == 0) atomicAdd(stats + m, sm);
        }
    }
}

// ---------------------------------------------------------------------------
// K2: finalize BN stats -> fused weights W' = scale*W, shift = beta - mean*scale
// ---------------------------------------------------------------------------
__global__ void k2_fin(const float* __restrict__ stats, const float* __restrict__ W,
                       const float* __restrict__ bnw, const float* __restrict__ bnb,
                       float* __restrict__ wp) {
    const int o = threadIdx.x;  // 64 threads
    float m[6];
#pragma unroll
    for (int c = 0; c < 6; ++c) m[c] = stats[c];
    float S[6][6];
    int p = 6;
#pragma unroll
    for (int a = 0; a < 6; ++a)
#pragma unroll
        for (int bb = a; bb < 6; ++bb) { S[a][bb] = stats[p]; S[bb][a] = stats[p]; ++p; }
    float w[6];
#pragma unroll
    for (int c = 0; c < 6; ++c) w[c] = W[o * 6 + c];

    const float invM = 1.f / (float)M_TOT;
    float mean = 0.f;
#pragma unroll
    for (int c = 0; c < 6; ++c) mean += w[c] * m[c];
    mean *= invM;
    float ey2 = 0.f;
#pragma unroll
    for (int a = 0; a < 6; ++a)
#pragma unroll
        for (int bb = 0; bb < 6; ++bb) ey2 += w[a] * w[bb] * S[a][bb];
    ey2 *= invM;
    float var   = ey2 - mean * mean;
    float scale = bnw[o] * rsqrtf(var + 1e-5f);
    float shift = bnb[o] - mean * scale;
#pragma unroll
    for (int c = 0; c < 6; ++c) wp[o * 8 + c] = w[c] * scale;
    wp[o * 8 + 6] = shift;
    wp[o * 8 + 7] = 0.f;
}

// ---------------------------------------------------------------------------
// K3: per (b,n): gather 20 neighbor deltas, fused conv+BN+relu+max.
// 64 points/block, 4 threads/point (16 channels each); lane = point ->
// coalesced stores. idx staged in LDS. 512 blocks -> 2 blocks/CU.
// ---------------------------------------------------------------------------
__global__ __launch_bounds__(256, 2) void k3_out(const float* __restrict__ x,
                                                 const float* __restrict__ wp,
                                                 const int* __restrict__ idxbuf,
                                                 float* __restrict__ out) {
    __shared__ float4 pts[N_];          // 32 KB
    __shared__ float  lwp[OD * 8];      // 2 KB
    __shared__ int    sidx[PPB * KNN];  // 5 KB

    const int b     = blockIdx.x >> 5;  // 32 chunks of 64 points per batch
    const int chunk = blockIdx.x & 31;
    const int t     = threadIdx.x;

    const float* xb = x + b * 3 * N_;
    for (int n = t; n < N_; n += 256)
        pts[n] = make_float4(xb[n], xb[N_ + n], xb[2 * N_ + n], 0.f);
    for (int q = t; q < OD * 8; q += 256) lwp[q] = wp[q];
    {
        const int* ib = idxbuf + (b * N_ + chunk * 64) * KNN;
        for (int i = t; i < PPB * KNN; i += 256) sidx[i] = ib[i];
    }
    __syncthreads();

    const int nl  = t & 63;             // lane = point -> coalesced stores
    const int sub = t >> 6;             // channel quarter
    const int n   = chunk * 64 + nl;
    const float4 pi = pts[n];

    float e0[KNN], e1[KNN], e2[KNN];
#pragma unroll
    for (int r = 0; r < KNN; ++r) {
        int j = sidx[nl * KNN + r];
        float4 pj = pts[j];
        e0[r] = pj.x - pi.x;
        e1[r] = pj.y - pi.y;
        e2[r] = pj.z - pi.z;
    }

    float* ob = out + (size_t)b * OD * N_ + n;
    const int o0 = sub * 16;
#pragma unroll 4
    for (int o = o0; o < o0 + 16; ++o) {
        float w0 = lwp[o * 8 + 0], w1 = lwp[o * 8 + 1], w2 = lwp[o * 8 + 2];
        float w3 = lwp[o * 8 + 3], w4 = lwp[o * 8 + 4], w5 = lwp[o * 8 + 5];
        float base = lwp[o * 8 + 6];
        base = fmaf(w3, pi.x, base);
        base = fmaf(w4, pi.y, base);
        base = fmaf(w5, pi.z, base);
        float acc = 0.f;  // relu folded into init
#pragma unroll
        for (int r = 0; r < KNN; ++r) {
            float y = base;
            y = fmaf(w0, e0[r], y);
            y = fmaf(w1, e1[r], y);
            y = fmaf(w2, e2[r], y);
            acc = fmaxf(acc, y);
        }
        ob[(size_t)o * N_] = acc;
    }
}

// ---------------------------------------------------------------------------
extern "C" void kernel_launch(void* const* d_in, const int* in_sizes, int n_in,
                              void* d_out, int out_size, void* d_ws, size_t ws_size,
                              hipStream_t stream) {
    const float* x   = (const float*)d_in[0];
    const float* W   = (const float*)d_in[1];
    const float* bnw = (const float*)d_in[2];
    const float* bnb = (const float*)d_in[3];
    float* out = (float*)d_out;

    float* stats  = (float*)d_ws;                       // 27 floats
    float* wp     = (float*)((char*)d_ws + 1024);       // 64*8 floats
    int*   idxbuf = (int*)((char*)d_ws + 4096);         // B*N*K ints (~2.6 MB)

    hipMemsetAsync(d_ws, 0, 128, stream);
    k1_knn<<<dim3(512), dim3(512), 0, stream>>>(x, stats, idxbuf);
    k2_fin<<<dim3(1), dim3(64), 0, stream>>>(stats, W, bnw, bnb, wp);
    k3_out<<<dim3(512), dim3(256), 0, stream>>>(x, wp, idxbuf, out);
}